// Round 2
// baseline (1024.653 us; speedup 1.0000x reference)
//
#include <hip/hip_runtime.h>

#define B_   8
#define C_   128
#define H_   96
#define W_   96
#define HO_  48
#define N_   2304          // HO_*WO_
#define K_CONV 1152        // C_*9
#define PLANE_IN  9216     // H_*W_
#define TOT_OUT (B_*C_*N_) // 2359296

__device__ __forceinline__ float block_reduce_sum_256(float v) {
  #pragma unroll
  for (int o = 32; o > 0; o >>= 1) v += __shfl_down(v, o, 64);
  __shared__ float r[4];
  int lane = threadIdx.x & 63, wv = threadIdx.x >> 6;
  if (lane == 0) r[wv] = v;
  __syncthreads();
  float s = 0.f;
  if (threadIdx.x == 0) s = r[0] + r[1] + r[2] + r[3];
  __syncthreads();
  return s;  // valid on thread 0 only
}

// ---------------- BN param prep: inv = w/sqrt(v+eps), beta = b - m*inv ------
__global__ void k_prep(const float* __restrict__ w, const float* __restrict__ bb,
                       const float* __restrict__ m, const float* __restrict__ v,
                       float* __restrict__ inv, float* __restrict__ beta) {
  int c = threadIdx.x;
  if (c < C_) {
    float iv = w[c] / sqrtf(v[c] + 1e-5f);
    inv[c] = iv;
    beta[c] = bb[c] - m[c] * iv;
  }
}

// ---------------- wx = relu(mean_{hw} x) -> wcat[b][0..127] -----------------
__global__ __launch_bounds__(256) void k_meanx(const float* __restrict__ x,
                                               float* __restrict__ wcat) {
  int bc = blockIdx.x;  // b*128+c
  const float* p = x + (size_t)bc * PLANE_IN;
  float s = 0.f;
  for (int i = threadIdx.x; i < PLANE_IN; i += 256) s += p[i];
  s = block_reduce_sum_256(s);
  if (threadIdx.x == 0) {
    int b = bc >> 7, c = bc & 127;
    wcat[b * 256 + c] = fmaxf(s * (1.f / PLANE_IN), 0.f);
  }
}

// ---------------- implicit-GEMM conv3x3 s2 p1 with fused BN+ReLU ------------
// out[b][co][n] = sum_{k=ci*9+kh*3+kw} W[co][k] * relu(x[b][ci][ih][iw]*inv+beta)
__global__ __launch_bounds__(256) void k_conv(const float* __restrict__ x,
                                              const float* __restrict__ w,
                                              const float* __restrict__ bias,
                                              const float* __restrict__ pinv,
                                              const float* __restrict__ pbeta,
                                              float* __restrict__ out) {
  __shared__ __align__(16) float As[16][64];  // [k][co]
  __shared__ __align__(16) float Bs[16][64];  // [k][n]
  const int b   = blockIdx.z;
  const int co0 = blockIdx.y * 64;
  const int n0  = blockIdx.x * 64;
  const int t   = threadIdx.x;
  const float* xb = x + (size_t)b * (C_ * PLANE_IN);
  const int a_co = t >> 2;
  const int a_k4 = (t & 3) * 4;
  const int b_k  = t >> 4;
  const int b_n4 = (t & 15) * 4;
  const int rl = (t >> 4) * 4;   // micro rows (co)
  const int cl = (t & 15) * 4;   // micro cols (n)
  float acc[4][4] = {{0.f}};
  int ohs[4], ows[4];
  #pragma unroll
  for (int j = 0; j < 4; ++j) {
    int n = n0 + b_n4 + j;
    ohs[j] = n / HO_;
    ows[j] = n - ohs[j] * HO_;
  }
  for (int k0 = 0; k0 < K_CONV; k0 += 16) {
    {  // A: weights
      const float* wp = w + (size_t)(co0 + a_co) * K_CONV + (k0 + a_k4);
      float4 raw = *(const float4*)wp;
      As[a_k4 + 0][a_co] = raw.x;
      As[a_k4 + 1][a_co] = raw.y;
      As[a_k4 + 2][a_co] = raw.z;
      As[a_k4 + 3][a_co] = raw.w;
    }
    {  // B: x gather with fused BN+ReLU; zero pad
      int k = k0 + b_k;
      int ci = k / 9;
      int r  = k - ci * 9;
      int kh = r / 3;
      int kw = r - kh * 3;
      float inv = pinv[ci], beta = pbeta[ci];
      const float* xc = xb + (size_t)ci * PLANE_IN;
      #pragma unroll
      for (int j = 0; j < 4; ++j) {
        int ih = 2 * ohs[j] + kh - 1;
        int iw = 2 * ows[j] + kw - 1;
        float vv = 0.f;
        if ((unsigned)ih < (unsigned)H_ && (unsigned)iw < (unsigned)W_)
          vv = fmaxf(xc[ih * W_ + iw] * inv + beta, 0.f);
        Bs[b_k][b_n4 + j] = vv;
      }
    }
    __syncthreads();
    #pragma unroll
    for (int kk = 0; kk < 16; ++kk) {
      float4 a  = *(const float4*)&As[kk][rl];
      float4 bv = *(const float4*)&Bs[kk][cl];
      acc[0][0] = fmaf(a.x, bv.x, acc[0][0]); acc[0][1] = fmaf(a.x, bv.y, acc[0][1]);
      acc[0][2] = fmaf(a.x, bv.z, acc[0][2]); acc[0][3] = fmaf(a.x, bv.w, acc[0][3]);
      acc[1][0] = fmaf(a.y, bv.x, acc[1][0]); acc[1][1] = fmaf(a.y, bv.y, acc[1][1]);
      acc[1][2] = fmaf(a.y, bv.z, acc[1][2]); acc[1][3] = fmaf(a.y, bv.w, acc[1][3]);
      acc[2][0] = fmaf(a.z, bv.x, acc[2][0]); acc[2][1] = fmaf(a.z, bv.y, acc[2][1]);
      acc[2][2] = fmaf(a.z, bv.z, acc[2][2]); acc[2][3] = fmaf(a.z, bv.w, acc[2][3]);
      acc[3][0] = fmaf(a.w, bv.x, acc[3][0]); acc[3][1] = fmaf(a.w, bv.y, acc[3][1]);
      acc[3][2] = fmaf(a.w, bv.z, acc[3][2]); acc[3][3] = fmaf(a.w, bv.w, acc[3][3]);
    }
    __syncthreads();
  }
  #pragma unroll
  for (int i = 0; i < 4; ++i) {
    float bi = bias[co0 + rl + i];
    float4 o = make_float4(acc[i][0] + bi, acc[i][1] + bi, acc[i][2] + bi, acc[i][3] + bi);
    *(float4*)&out[((size_t)b * C_ + co0 + rl + i) * N_ + (n0 + cl)] = o;
  }
}

// ---------------- scores[b][n][m] = sum_c f[b][c][n]*g[b][c][m] -------------
__global__ __launch_bounds__(256) void k_scores(const float* __restrict__ f,
                                                const float* __restrict__ g,
                                                float* __restrict__ attn) {
  __shared__ __align__(16) float As[16][64];  // [c][n]
  __shared__ __align__(16) float Bs[16][64];  // [c][m]
  const int b  = blockIdx.z;
  const int n0 = blockIdx.y * 64;
  const int m0 = blockIdx.x * 64;
  const int t  = threadIdx.x;
  const float* fb = f + (size_t)b * C_ * N_;
  const float* gb = g + (size_t)b * C_ * N_;
  const int lk = t >> 4, l4 = (t & 15) * 4;
  const int rl = (t >> 4) * 4, cl = (t & 15) * 4;
  float acc[4][4] = {{0.f}};
  for (int k0 = 0; k0 < C_; k0 += 16) {
    *(float4*)&As[lk][l4] = *(const float4*)&fb[(size_t)(k0 + lk) * N_ + n0 + l4];
    *(float4*)&Bs[lk][l4] = *(const float4*)&gb[(size_t)(k0 + lk) * N_ + m0 + l4];
    __syncthreads();
    #pragma unroll
    for (int kk = 0; kk < 16; ++kk) {
      float4 a  = *(const float4*)&As[kk][rl];
      float4 bv = *(const float4*)&Bs[kk][cl];
      acc[0][0] = fmaf(a.x, bv.x, acc[0][0]); acc[0][1] = fmaf(a.x, bv.y, acc[0][1]);
      acc[0][2] = fmaf(a.x, bv.z, acc[0][2]); acc[0][3] = fmaf(a.x, bv.w, acc[0][3]);
      acc[1][0] = fmaf(a.y, bv.x, acc[1][0]); acc[1][1] = fmaf(a.y, bv.y, acc[1][1]);
      acc[1][2] = fmaf(a.y, bv.z, acc[1][2]); acc[1][3] = fmaf(a.y, bv.w, acc[1][3]);
      acc[2][0] = fmaf(a.z, bv.x, acc[2][0]); acc[2][1] = fmaf(a.z, bv.y, acc[2][1]);
      acc[2][2] = fmaf(a.z, bv.z, acc[2][2]); acc[2][3] = fmaf(a.z, bv.w, acc[2][3]);
      acc[3][0] = fmaf(a.w, bv.x, acc[3][0]); acc[3][1] = fmaf(a.w, bv.y, acc[3][1]);
      acc[3][2] = fmaf(a.w, bv.z, acc[3][2]); acc[3][3] = fmaf(a.w, bv.w, acc[3][3]);
    }
    __syncthreads();
  }
  #pragma unroll
  for (int i = 0; i < 4; ++i) {
    float4 o = make_float4(acc[i][0], acc[i][1], acc[i][2], acc[i][3]);
    *(float4*)&attn[((size_t)b * N_ + n0 + rl + i) * N_ + (m0 + cl)] = o;
  }
}

// ---------------- in-place row softmax over m -------------------------------
__global__ __launch_bounds__(256) void k_softmax(float* __restrict__ attn) {
  float* row = attn + (size_t)blockIdx.x * N_;
  const int t = threadIdx.x;
  float v[9];
  float mx = -1e30f;
  #pragma unroll
  for (int i = 0; i < 9; ++i) { v[i] = row[t + 256 * i]; mx = fmaxf(mx, v[i]); }
  #pragma unroll
  for (int o = 32; o > 0; o >>= 1) mx = fmaxf(mx, __shfl_xor(mx, o, 64));
  __shared__ float red[4];
  int wv = t >> 6;
  if ((t & 63) == 0) red[wv] = mx;
  __syncthreads();
  mx = fmaxf(fmaxf(red[0], red[1]), fmaxf(red[2], red[3]));
  float sm = 0.f;
  #pragma unroll
  for (int i = 0; i < 9; ++i) { v[i] = __expf(v[i] - mx); sm += v[i]; }
  #pragma unroll
  for (int o = 32; o > 0; o >>= 1) sm += __shfl_xor(sm, o, 64);
  __syncthreads();
  if ((t & 63) == 0) red[wv] = sm;
  __syncthreads();
  sm = red[0] + red[1] + red[2] + red[3];
  float inv = 1.f / sm;
  #pragma unroll
  for (int i = 0; i < 9; ++i) row[t + 256 * i] = v[i] * inv;
}

// ---------------- s[b][c][m] = gamma * sum_n h[b][c][n]*attn[b][n][m] -------
__global__ __launch_bounds__(256) void k_sgemm(const float* __restrict__ h,
                                               const float* __restrict__ attn,
                                               const float* __restrict__ gammap,
                                               float* __restrict__ s) {
  __shared__ __align__(16) float As[16][64];  // [n][c]
  __shared__ __align__(16) float Bs[16][64];  // [n][m]
  const int b  = blockIdx.z;
  const int c0 = blockIdx.y * 64;
  const int m0 = blockIdx.x * 64;
  const int t  = threadIdx.x;
  const float* hb = h + (size_t)b * C_ * N_;
  const float* ab = attn + (size_t)b * N_ * N_;
  const int a_c = t >> 2, a_k4 = (t & 3) * 4;
  const int lk = t >> 4, l4 = (t & 15) * 4;
  const int rl = (t >> 4) * 4, cl = (t & 15) * 4;
  float acc[4][4] = {{0.f}};
  for (int k0 = 0; k0 < N_; k0 += 16) {
    float4 av = *(const float4*)&hb[(size_t)(c0 + a_c) * N_ + k0 + a_k4];
    As[a_k4 + 0][a_c] = av.x;
    As[a_k4 + 1][a_c] = av.y;
    As[a_k4 + 2][a_c] = av.z;
    As[a_k4 + 3][a_c] = av.w;
    *(float4*)&Bs[lk][l4] = *(const float4*)&ab[(size_t)(k0 + lk) * N_ + m0 + l4];
    __syncthreads();
    #pragma unroll
    for (int kk = 0; kk < 16; ++kk) {
      float4 a  = *(const float4*)&As[kk][rl];
      float4 bv = *(const float4*)&Bs[kk][cl];
      acc[0][0] = fmaf(a.x, bv.x, acc[0][0]); acc[0][1] = fmaf(a.x, bv.y, acc[0][1]);
      acc[0][2] = fmaf(a.x, bv.z, acc[0][2]); acc[0][3] = fmaf(a.x, bv.w, acc[0][3]);
      acc[1][0] = fmaf(a.y, bv.x, acc[1][0]); acc[1][1] = fmaf(a.y, bv.y, acc[1][1]);
      acc[1][2] = fmaf(a.y, bv.z, acc[1][2]); acc[1][3] = fmaf(a.y, bv.w, acc[1][3]);
      acc[2][0] = fmaf(a.z, bv.x, acc[2][0]); acc[2][1] = fmaf(a.z, bv.y, acc[2][1]);
      acc[2][2] = fmaf(a.z, bv.z, acc[2][2]); acc[2][3] = fmaf(a.z, bv.w, acc[2][3]);
      acc[3][0] = fmaf(a.w, bv.x, acc[3][0]); acc[3][1] = fmaf(a.w, bv.y, acc[3][1]);
      acc[3][2] = fmaf(a.w, bv.z, acc[3][2]); acc[3][3] = fmaf(a.w, bv.w, acc[3][3]);
    }
    __syncthreads();
  }
  const float gv = gammap[0];
  #pragma unroll
  for (int i = 0; i < 4; ++i) {
    float4 o = make_float4(gv * acc[i][0], gv * acc[i][1], gv * acc[i][2], gv * acc[i][3]);
    *(float4*)&s[((size_t)b * C_ + c0 + rl + i) * N_ + (m0 + cl)] = o;
  }
}

// ---------------- ws = relu(mean_m s) -> wcat[b][128..255] ------------------
__global__ __launch_bounds__(256) void k_means(const float* __restrict__ s,
                                               float* __restrict__ wcat) {
  int bc = blockIdx.x;  // b*128+c
  const float* p = s + (size_t)bc * N_;
  float sm = 0.f;
  for (int i = threadIdx.x; i < N_; i += 256) sm += p[i];
  sm = block_reduce_sum_256(sm);
  if (threadIdx.x == 0) {
    int b = bc >> 7, c = bc & 127;
    wcat[b * 256 + 128 + c] = fmaxf(sm * (1.f / N_), 0.f);
  }
}

// ---------------- SE MLP: 256 -> 42 (relu) -> 128 ---------------------------
__global__ __launch_bounds__(128) void k_se(const float* __restrict__ wcat,
                                            const float* __restrict__ cw,
                                            const float* __restrict__ cb,
                                            const float* __restrict__ uw,
                                            const float* __restrict__ ub,
                                            float* __restrict__ se) {
  const int b = blockIdx.x, t = threadIdx.x;
  __shared__ float wc[256];
  __shared__ float s1[42];
  wc[t] = wcat[b * 256 + t];
  wc[128 + t] = wcat[b * 256 + 128 + t];
  __syncthreads();
  if (t < 42) {
    float a = cb[t];
    const float* r = cw + (size_t)t * 256;
    for (int k = 0; k < 256; ++k) a += wc[k] * r[k];
    s1[t] = fmaxf(a, 0.f);
  }
  __syncthreads();
  {
    float a = ub[t];
    const float* r = uw + (size_t)t * 42;
    for (int j = 0; j < 42; ++j) a += s1[j] * r[j];
    se[b * 128 + t] = a;
  }
}

// ---------------- out = (avgpool2x2(x) + s) * (1 + se) ----------------------
__global__ __launch_bounds__(256) void k_final(const float* __restrict__ x,
                                               const float* __restrict__ s,
                                               const float* __restrict__ se,
                                               float* __restrict__ out) {
  int idx = blockIdx.x * 256 + threadIdx.x;
  if (idx >= TOT_OUT) return;
  int m  = idx % N_;
  int bc = idx / N_;  // b*128+c
  int oh = m / HO_, ow = m - oh * HO_;
  const float* xp = x + (size_t)bc * PLANE_IN;
  int ih = oh * 2, iw = ow * 2;
  float l = 0.25f * (xp[ih * W_ + iw] + xp[ih * W_ + iw + 1] +
                     xp[(ih + 1) * W_ + iw] + xp[(ih + 1) * W_ + iw + 1]);
  out[idx] = (l + s[idx]) * (1.f + se[bc]);
}

extern "C" void kernel_launch(void* const* d_in, const int* in_sizes, int n_in,
                              void* d_out, int out_size, void* d_ws, size_t ws_size,
                              hipStream_t stream) {
  (void)in_sizes; (void)n_in; (void)out_size; (void)ws_size;
  const float* x    = (const float*)d_in[0];
  const float* bnw[3] = {(const float*)d_in[1],  (const float*)d_in[7],  (const float*)d_in[13]};
  const float* bnb[3] = {(const float*)d_in[2],  (const float*)d_in[8],  (const float*)d_in[14]};
  const float* bnm[3] = {(const float*)d_in[3],  (const float*)d_in[9],  (const float*)d_in[15]};
  const float* bnv[3] = {(const float*)d_in[4],  (const float*)d_in[10], (const float*)d_in[16]};
  const float* cw_[3] = {(const float*)d_in[5],  (const float*)d_in[11], (const float*)d_in[17]};
  const float* cbb[3] = {(const float*)d_in[6],  (const float*)d_in[12], (const float*)d_in[18]};
  const float* secw = (const float*)d_in[19];
  const float* secb = (const float*)d_in[20];
  const float* seuw = (const float*)d_in[21];
  const float* seub = (const float*)d_in[22];
  const float* gamma = (const float*)d_in[23];
  float* out = (float*)d_out;

  char* ws = (char*)d_ws;
  size_t off = 0;
  auto alloc = [&](size_t bytes) -> char* {
    char* p = ws + off;
    off = (off + bytes + 255) & ~(size_t)255;
    return p;
  };
  float* attn  = (float*)alloc((size_t)B_ * N_ * N_ * 4);
  float* fbuf  = (float*)alloc((size_t)B_ * C_ * N_ * 4);
  float* gbuf  = (float*)alloc((size_t)B_ * C_ * N_ * 4);
  float* hbuf  = (float*)alloc((size_t)B_ * C_ * N_ * 4);
  float* sbuf  = (float*)alloc((size_t)B_ * C_ * N_ * 4);
  float* wcat  = (float*)alloc(B_ * 256 * 4);
  float* sebuf = (float*)alloc(B_ * 128 * 4);
  float* pinv  = (float*)alloc(3 * 128 * 4);
  float* pbeta = (float*)alloc(3 * 128 * 4);
  float* fgh[3] = {fbuf, gbuf, hbuf};

  for (int p = 0; p < 3; ++p)
    k_prep<<<1, 128, 0, stream>>>(bnw[p], bnb[p], bnm[p], bnv[p], pinv + p * 128, pbeta + p * 128);

  k_meanx<<<B_ * C_, 256, 0, stream>>>(x, wcat);

  for (int p = 0; p < 3; ++p)
    k_conv<<<dim3(N_ / 64, C_ / 64, B_), 256, 0, stream>>>(x, cw_[p], cbb[p],
                                                           pinv + p * 128, pbeta + p * 128, fgh[p]);

  k_scores<<<dim3(N_ / 64, N_ / 64, B_), 256, 0, stream>>>(fbuf, gbuf, attn);
  k_softmax<<<B_ * N_, 256, 0, stream>>>(attn);
  k_sgemm<<<dim3(N_ / 64, C_ / 64, B_), 256, 0, stream>>>(hbuf, attn, gamma, sbuf);

  k_means<<<B_ * C_, 256, 0, stream>>>(sbuf, wcat);
  k_se<<<B_, 128, 0, stream>>>(wcat, secw, secb, seuw, seub, sebuf);

  k_final<<<(TOT_OUT + 255) / 256, 256, 0, stream>>>(x, sbuf, sebuf, out);
}

// Round 4
// 378.327 us; speedup vs baseline: 2.7084x; 2.7084x over previous
//
#include <hip/hip_runtime.h>
#include <hip/hip_bf16.h>

#define B_   8
#define C_   128
#define H_   96
#define W_   96
#define HP_  98            // padded H/W
#define HO_  48
#define N_   2304          // HO_*HO_
#define K_CONV 1152        // C_*9
#define PLANE_IN  9216     // H_*W_
#define TOT_OUT (B_*C_*N_)

typedef __attribute__((ext_vector_type(8))) short          s16x8;
typedef __attribute__((ext_vector_type(8))) unsigned short u16x8;
typedef __attribute__((ext_vector_type(4))) unsigned short u16x4;
typedef __attribute__((ext_vector_type(4))) float          f32x4;

// XOR-swizzled byte offset for [row][32k] bf16 tiles (64 B rows, 16 B granules)
#define SW(row, q) (((row) << 6) + ((((q) ^ (((row) >> 1) & 3))) << 4))

__device__ __forceinline__ ushort f2bf(float f) {
  __hip_bfloat16 h = __float2bfloat16(f);
  return *reinterpret_cast<ushort*>(&h);
}
__device__ __forceinline__ float bf2f(ushort u) {
  return __uint_as_float(((unsigned int)u) << 16);
}

__device__ __forceinline__ float block_reduce_sum_256(float v) {
  #pragma unroll
  for (int o = 32; o > 0; o >>= 1) v += __shfl_down(v, o, 64);
  __shared__ float r[4];
  int lane = threadIdx.x & 63, wv = threadIdx.x >> 6;
  if (lane == 0) r[wv] = v;
  __syncthreads();
  float s = 0.f;
  if (threadIdx.x == 0) s = r[0] + r[1] + r[2] + r[3];
  __syncthreads();
  return s;  // valid on thread 0 only
}

// ---------------- BN param prep ---------------------------------------------
__global__ void k_prep(const float* __restrict__ w, const float* __restrict__ bb,
                       const float* __restrict__ m, const float* __restrict__ v,
                       float* __restrict__ inv, float* __restrict__ beta) {
  int c = threadIdx.x;
  if (c < C_) {
    float iv = w[c] / sqrtf(v[c] + 1e-5f);
    inv[c] = iv;
    beta[c] = bb[c] - m[c] * iv;
  }
}

// ---------------- conv weights fp32 OIHW -> bf16 [co][(kh*3+kw)*128+ci] -----
__global__ __launch_bounds__(256) void k_prep_w(const float* __restrict__ w,
                                                ushort* __restrict__ wb) {
  int id = blockIdx.x * 256 + threadIdx.x;
  if (id >= C_ * K_CONV) return;
  int co = id / K_CONV, rem = id - co * K_CONV;
  int tap = rem >> 7, ci = rem & 127;
  wb[id] = f2bf(w[co * K_CONV + ci * 9 + tap]);
}

// ---------------- x -> 3x padded NHWC bf16 y (BN+ReLU fused) ----------------
__global__ __launch_bounds__(256) void k_prep_y(const float* __restrict__ x,
                                                const float* __restrict__ pinv,
                                                const float* __restrict__ pbeta,
                                                ushort* __restrict__ y0,
                                                ushort* __restrict__ y1,
                                                ushort* __restrict__ y2) {
  const int h1 = blockIdx.x, b = blockIdx.y, t = threadIdx.x;
  ushort* ys[3] = {y0 + (size_t)b * HP_ * HP_ * C_,
                   y1 + (size_t)b * HP_ * HP_ * C_,
                   y2 + (size_t)b * HP_ * HP_ * C_};
  u16x8 zer = (u16x8)0;
  if (h1 == 0 || h1 == HP_ - 1) {
    for (int p = 0; p < 3; ++p)
      for (int g = t; g < HP_ * C_ / 8; g += 256)
        *(u16x8*)(ys[p] + (size_t)h1 * HP_ * C_ + g * 8) = zer;
    return;
  }
  __shared__ float xs[128][97];
  const int h = h1 - 1;
  const float* xb = x + (size_t)b * C_ * PLANE_IN + h * W_;
  for (int id = t; id < 128 * 24; id += 256) {
    int ci = id / 24, w4 = id - ci * 24;
    float4 v = *(const float4*)(xb + (size_t)ci * PLANE_IN + w4 * 4);
    xs[ci][w4 * 4 + 0] = v.x; xs[ci][w4 * 4 + 1] = v.y;
    xs[ci][w4 * 4 + 2] = v.z; xs[ci][w4 * 4 + 3] = v.w;
  }
  __syncthreads();
  // edge pixels w1=0, w1=97
  if (t < 32) {
    int side = t >> 4, cg = t & 15;
    for (int p = 0; p < 3; ++p)
      *(u16x8*)(ys[p] + ((size_t)h1 * HP_ + (side ? HP_ - 1 : 0)) * C_ + cg * 8) = zer;
  }
  for (int p = 0; p < 3; ++p) {
    const float* inv = pinv + p * 128;
    const float* bet = pbeta + p * 128;
    for (int g = t; g < 96 * 16; g += 256) {
      int wdx = g >> 4, cg = g & 15;
      u16x8 o;
      #pragma unroll
      for (int k = 0; k < 8; ++k) {
        int ci = cg * 8 + k;
        o[k] = f2bf(fmaxf(xs[ci][wdx] * inv[ci] + bet[ci], 0.f));
      }
      *(u16x8*)(ys[p] + ((size_t)h1 * HP_ + (wdx + 1)) * C_ + cg * 8) = o;
    }
  }
}

// ---------------- wx = relu(mean_{hw} x) ------------------------------------
__global__ __launch_bounds__(256) void k_meanx(const float* __restrict__ x,
                                               float* __restrict__ wcat) {
  int bc = blockIdx.x;
  const float* p = x + (size_t)bc * PLANE_IN;
  float s = 0.f;
  for (int i = threadIdx.x; i < PLANE_IN; i += 256) s += p[i];
  s = block_reduce_sum_256(s);
  if (threadIdx.x == 0) {
    int b = bc >> 7, c = bc & 127;
    wcat[b * 256 + c] = fmaxf(s * (1.f / PLANE_IN), 0.f);
  }
}

// ---------------- MFMA implicit-GEMM conv: M=128co x N=64pos x K=1152 -------
// mode 0: out[b][n][c] bf16 (f,g)   mode 1: out[b][c][n] bf16 (h)
__global__ __launch_bounds__(256) void k_conv(const ushort* __restrict__ y_all,
                                              const ushort* __restrict__ wb,
                                              const float* __restrict__ bias,
                                              ushort* __restrict__ out, int mode) {
  __shared__ __align__(16) char smem[16384];
  char* As = smem;          // 128 rows x 64 B (swizzled)
  char* Bs = smem + 8192;   // 64 rows x 64 B (swizzled)
  const int b = blockIdx.z, n0 = blockIdx.x * 64;
  const int t = threadIdx.x, l = t & 63, w = t >> 6;
  const ushort* yb = y_all + (size_t)b * HP_ * HP_ * C_;
  const int pos = t >> 2, q = t & 3;         // B staging assignment
  const int n_glob = n0 + pos;               // FIX r3: global position, was `pos`
  const int oh = n_glob / HO_, ow = n_glob - oh * HO_;
  const int mh = (w & 1) * 64, nh = (w >> 1) * 32;
  f32x4 acc[4][2];
  #pragma unroll
  for (int i = 0; i < 4; ++i)
    #pragma unroll
    for (int j = 0; j < 2; ++j) acc[i][j] = (f32x4)0.f;

  for (int k0 = 0; k0 < K_CONV; k0 += 32) {
    int tap = k0 >> 7, ci0 = k0 & 127;
    int kh = tap / 3, kw = tap - kh * 3;
    #pragma unroll
    for (int g2 = 0; g2 < 2; ++g2) {   // A: 512 granules
      int g = t + g2 * 256, row = g >> 2, qq = g & 3;
      u16x8 d = *(const u16x8*)(wb + row * K_CONV + k0 + qq * 8);
      *(u16x8*)(As + SW(row, qq)) = d;
    }
    {   // B: 256 granules
      int h1 = 2 * oh + kh, w1 = 2 * ow + kw;
      u16x8 d = *(const u16x8*)(yb + ((size_t)h1 * HP_ + w1) * C_ + ci0 + q * 8);
      *(u16x8*)(Bs + SW(pos, q)) = d;
    }
    __syncthreads();
    s16x8 af[4], bf[2];
    #pragma unroll
    for (int i = 0; i < 4; ++i) {
      int r = mh + i * 16 + (l & 15);
      af[i] = *(const s16x8*)(As + SW(r, (l >> 4)));
    }
    #pragma unroll
    for (int j = 0; j < 2; ++j) {
      int r = nh + j * 16 + (l & 15);
      bf[j] = *(const s16x8*)(Bs + SW(r, (l >> 4)));
    }
    #pragma unroll
    for (int i = 0; i < 4; ++i)
      #pragma unroll
      for (int j = 0; j < 2; ++j)
        acc[i][j] = __builtin_amdgcn_mfma_f32_16x16x32_bf16(af[i], bf[j], acc[i][j], 0, 0, 0);
    __syncthreads();
  }

  if (mode == 0) {  // out[b][n][c]
    #pragma unroll
    for (int i = 0; i < 4; ++i) {
      int co4 = mh + i * 16 + (l >> 4) * 4;
      float4 bi = *(const float4*)&bias[co4];
      #pragma unroll
      for (int j = 0; j < 2; ++j) {
        int pp = nh + j * 16 + (l & 15);
        u16x4 o;
        o[0] = f2bf(acc[i][j][0] + bi.x); o[1] = f2bf(acc[i][j][1] + bi.y);
        o[2] = f2bf(acc[i][j][2] + bi.z); o[3] = f2bf(acc[i][j][3] + bi.w);
        *(u16x4*)(out + ((size_t)b * N_ + n0 + pp) * C_ + co4) = o;
      }
    }
  } else {          // out[b][c][n] via LDS bounce
    ushort* tb = (ushort*)smem;  // [co][64 pos]
    #pragma unroll
    for (int i = 0; i < 4; ++i) {
      int co4 = mh + i * 16 + (l >> 4) * 4;
      float4 bi = *(const float4*)&bias[co4];
      float bia[4] = {bi.x, bi.y, bi.z, bi.w};
      #pragma unroll
      for (int j = 0; j < 2; ++j) {
        int pp = nh + j * 16 + (l & 15);
        #pragma unroll
        for (int r = 0; r < 4; ++r)
          tb[(co4 + r) * 64 + pp] = f2bf(acc[i][j][r] + bia[r]);
      }
    }
    __syncthreads();
    for (int g = t; g < 1024; g += 256) {
      int co = g >> 3, off = (g & 7) * 8;
      u16x8 d = *(const u16x8*)(tb + co * 64 + off);
      *(u16x8*)(out + ((size_t)b * C_ + co) * N_ + n0 + off) = d;
    }
  }
}

// ---------------- scores: D[n][m] bf16 = sum_c f[n][c]*g[m][c] --------------
__global__ __launch_bounds__(256) void k_scores(const ushort* __restrict__ f,
                                                const ushort* __restrict__ g,
                                                ushort* __restrict__ attn) {
  __shared__ __align__(16) char smem[16384];
  char* As = smem;          // 128 n-rows x 64 B
  char* Bs = smem + 8192;   // 128 m-rows x 64 B
  const int b = blockIdx.z, n0 = blockIdx.y * 128, m0 = blockIdx.x * 128;
  const int t = threadIdx.x, l = t & 63, w = t >> 6;
  const ushort* fb = f + (size_t)b * N_ * C_;
  const ushort* gb = g + (size_t)b * N_ * C_;
  const int a0 = (w & 1) * 64, b0 = (w >> 1) * 64;
  f32x4 acc[4][4];
  #pragma unroll
  for (int i = 0; i < 4; ++i)
    #pragma unroll
    for (int j = 0; j < 4; ++j) acc[i][j] = (f32x4)0.f;

  for (int k0 = 0; k0 < C_; k0 += 32) {
    #pragma unroll
    for (int g2 = 0; g2 < 2; ++g2) {
      int gg = t + g2 * 256, row = gg >> 2, qq = gg & 3;
      *(u16x8*)(As + SW(row, qq)) = *(const u16x8*)(fb + (size_t)(n0 + row) * C_ + k0 + qq * 8);
      *(u16x8*)(Bs + SW(row, qq)) = *(const u16x8*)(gb + (size_t)(m0 + row) * C_ + k0 + qq * 8);
    }
    __syncthreads();
    s16x8 af[4], bf[4];
    #pragma unroll
    for (int i = 0; i < 4; ++i)
      af[i] = *(const s16x8*)(As + SW(a0 + i * 16 + (l & 15), (l >> 4)));
    #pragma unroll
    for (int j = 0; j < 4; ++j)
      bf[j] = *(const s16x8*)(Bs + SW(b0 + j * 16 + (l & 15), (l >> 4)));
    #pragma unroll
    for (int i = 0; i < 4; ++i)
      #pragma unroll
      for (int j = 0; j < 4; ++j)
        acc[i][j] = __builtin_amdgcn_mfma_f32_16x16x32_bf16(af[i], bf[j], acc[i][j], 0, 0, 0);
    __syncthreads();
  }
  #pragma unroll
  for (int i = 0; i < 4; ++i) {
    int n4 = n0 + a0 + i * 16 + (l >> 4) * 4;
    #pragma unroll
    for (int j = 0; j < 4; ++j) {
      int m = m0 + b0 + j * 16 + (l & 15);
      #pragma unroll
      for (int r = 0; r < 4; ++r)
        attn[((size_t)b * N_ + n4 + r) * N_ + m] = f2bf(acc[i][j][r]);
    }
  }
}

// ---------------- in-place row softmax (bf16 rows, fp32 internal) -----------
__global__ __launch_bounds__(256) void k_softmax(ushort* __restrict__ attn) {
  ushort* row = attn + (size_t)blockIdx.x * N_;
  const int t = threadIdx.x;
  float v[9];
  float mx = -1e30f;
  #pragma unroll
  for (int i = 0; i < 9; ++i) { v[i] = bf2f(row[t + 256 * i]); mx = fmaxf(mx, v[i]); }
  #pragma unroll
  for (int o = 32; o > 0; o >>= 1) mx = fmaxf(mx, __shfl_xor(mx, o, 64));
  __shared__ float red[4];
  int wv = t >> 6;
  if ((t & 63) == 0) red[wv] = mx;
  __syncthreads();
  mx = fmaxf(fmaxf(red[0], red[1]), fmaxf(red[2], red[3]));
  float sm = 0.f;
  #pragma unroll
  for (int i = 0; i < 9; ++i) { v[i] = __expf(v[i] - mx); sm += v[i]; }
  #pragma unroll
  for (int o = 32; o > 0; o >>= 1) sm += __shfl_xor(sm, o, 64);
  __syncthreads();
  if ((t & 63) == 0) red[wv] = sm;
  __syncthreads();
  sm = red[0] + red[1] + red[2] + red[3];
  float inv = 1.f / sm;
  #pragma unroll
  for (int i = 0; i < 9; ++i) row[t + 256 * i] = f2bf(v[i] * inv);
}

// ---------------- sgemm: s[c][m] fp32 = gamma * sum_n h[c][n]*attn[n][m] ----
__global__ __launch_bounds__(256) void k_sgemm(const ushort* __restrict__ h,
                                               const ushort* __restrict__ attn,
                                               const float* __restrict__ gammap,
                                               float* __restrict__ s) {
  __shared__ __align__(16) char smem[16384];
  char* As = smem;                       // 128 c-rows x 64 B (swizzled)
  ushort* BsU = (ushort*)(smem + 8192);  // [32 k][128 m] plain
  const int b = blockIdx.z, m0 = blockIdx.x * 128;
  const int t = threadIdx.x, l = t & 63, w = t >> 6;
  const ushort* hb = h + (size_t)b * C_ * N_;
  const ushort* ab = attn + (size_t)b * N_ * N_;
  const int a0 = (w & 1) * 64, b0 = (w >> 1) * 64;
  f32x4 acc[4][4];
  #pragma unroll
  for (int i = 0; i < 4; ++i)
    #pragma unroll
    for (int j = 0; j < 4; ++j) acc[i][j] = (f32x4)0.f;

  for (int k0 = 0; k0 < N_; k0 += 32) {
    #pragma unroll
    for (int g2 = 0; g2 < 2; ++g2) {
      int gg = t + g2 * 256;
      int row = gg >> 2, qq = gg & 3;                 // A granule
      *(u16x8*)(As + SW(row, qq)) = *(const u16x8*)(hb + (size_t)row * N_ + k0 + qq * 8);
      int kr = gg >> 4, mo = (gg & 15) * 8;           // B granule
      *(u16x8*)(BsU + kr * 128 + mo) = *(const u16x8*)(ab + (size_t)(k0 + kr) * N_ + m0 + mo);
    }
    __syncthreads();
    s16x8 af[4], bf[4];
    #pragma unroll
    for (int i = 0; i < 4; ++i)
      af[i] = *(const s16x8*)(As + SW(a0 + i * 16 + (l & 15), (l >> 4)));
    const int qb = (l >> 4) * 8;
    #pragma unroll
    for (int j = 0; j < 4; ++j) {
      int m = b0 + j * 16 + (l & 15);
      union { s16x8 v; ushort u[8]; } bu;
      #pragma unroll
      for (int jj = 0; jj < 8; ++jj) bu.u[jj] = BsU[(qb + jj) * 128 + m];
      bf[j] = bu.v;
    }
    #pragma unroll
    for (int i = 0; i < 4; ++i)
      #pragma unroll
      for (int j = 0; j < 4; ++j)
        acc[i][j] = __builtin_amdgcn_mfma_f32_16x16x32_bf16(af[i], bf[j], acc[i][j], 0, 0, 0);
    __syncthreads();
  }
  const float gv = gammap[0];
  #pragma unroll
  for (int i = 0; i < 4; ++i) {
    int c4 = a0 + i * 16 + (l >> 4) * 4;
    #pragma unroll
    for (int j = 0; j < 4; ++j) {
      int m = m0 + b0 + j * 16 + (l & 15);
      #pragma unroll
      for (int r = 0; r < 4; ++r)
        s[((size_t)b * C_ + c4 + r) * N_ + m] = gv * acc[i][j][r];
    }
  }
}

// ---------------- ws = relu(mean_m s) ---------------------------------------
__global__ __launch_bounds__(256) void k_means(const float* __restrict__ s,
                                               float* __restrict__ wcat) {
  int bc = blockIdx.x;
  const float* p = s + (size_t)bc * N_;
  float sm = 0.f;
  for (int i = threadIdx.x; i < N_; i += 256) sm += p[i];
  sm = block_reduce_sum_256(sm);
  if (threadIdx.x == 0) {
    int b = bc >> 7, c = bc & 127;
    wcat[b * 256 + 128 + c] = fmaxf(sm * (1.f / N_), 0.f);
  }
}

// ---------------- SE MLP: 256 -> 42 (relu) -> 128 ---------------------------
__global__ __launch_bounds__(128) void k_se(const float* __restrict__ wcat,
                                            const float* __restrict__ cw,
                                            const float* __restrict__ cb,
                                            const float* __restrict__ uw,
                                            const float* __restrict__ ub,
                                            float* __restrict__ se) {
  const int b = blockIdx.x, t = threadIdx.x;
  __shared__ float wc[256];
  __shared__ float s1[42];
  wc[t] = wcat[b * 256 + t];
  wc[128 + t] = wcat[b * 256 + 128 + t];
  __syncthreads();
  if (t < 42) {
    float a = cb[t];
    const float* r = cw + (size_t)t * 256;
    for (int k = 0; k < 256; ++k) a += wc[k] * r[k];
    s1[t] = fmaxf(a, 0.f);
  }
  __syncthreads();
  {
    float a = ub[t];
    const float* r = uw + (size_t)t * 42;
    for (int j = 0; j < 42; ++j) a += s1[j] * r[j];
    se[b * 128 + t] = a;
  }
}

// ---------------- out = (avgpool2x2(x) + s) * (1 + se) ----------------------
__global__ __launch_bounds__(256) void k_final(const float* __restrict__ x,
                                               const float* __restrict__ s,
                                               const float* __restrict__ se,
                                               float* __restrict__ out) {
  int idx = blockIdx.x * 256 + threadIdx.x;
  if (idx >= TOT_OUT) return;
  int m  = idx % N_;
  int bc = idx / N_;
  int oh = m / HO_, ow = m - oh * HO_;
  const float* xp = x + (size_t)bc * PLANE_IN;
  int ih = oh * 2, iw = ow * 2;
  float l = 0.25f * (xp[ih * W_ + iw] + xp[ih * W_ + iw + 1] +
                     xp[(ih + 1) * W_ + iw] + xp[(ih + 1) * W_ + iw + 1]);
  out[idx] = (l + s[idx]) * (1.f + se[bc]);
}

extern "C" void kernel_launch(void* const* d_in, const int* in_sizes, int n_in,
                              void* d_out, int out_size, void* d_ws, size_t ws_size,
                              hipStream_t stream) {
  (void)in_sizes; (void)n_in; (void)out_size; (void)ws_size;
  const float* x    = (const float*)d_in[0];
  const float* bnw[3] = {(const float*)d_in[1],  (const float*)d_in[7],  (const float*)d_in[13]};
  const float* bnb[3] = {(const float*)d_in[2],  (const float*)d_in[8],  (const float*)d_in[14]};
  const float* bnm[3] = {(const float*)d_in[3],  (const float*)d_in[9],  (const float*)d_in[15]};
  const float* bnv[3] = {(const float*)d_in[4],  (const float*)d_in[10], (const float*)d_in[16]};
  const float* cw_[3] = {(const float*)d_in[5],  (const float*)d_in[11], (const float*)d_in[17]};
  const float* cbb[3] = {(const float*)d_in[6],  (const float*)d_in[12], (const float*)d_in[18]};
  const float* secw = (const float*)d_in[19];
  const float* secb = (const float*)d_in[20];
  const float* seuw = (const float*)d_in[21];
  const float* seub = (const float*)d_in[22];
  const float* gamma = (const float*)d_in[23];
  float* out = (float*)d_out;

  char* ws = (char*)d_ws;
  size_t off = 0;
  auto alloc = [&](size_t bytes) -> char* {
    char* p = ws + off;
    off = (off + bytes + 255) & ~(size_t)255;
    return p;
  };
  ushort* attn = (ushort*)alloc((size_t)B_ * N_ * N_ * 2);       // 85 MB bf16
  ushort* yp[3];
  for (int p = 0; p < 3; ++p) yp[p] = (ushort*)alloc((size_t)B_ * HP_ * HP_ * C_ * 2);
  ushort* wb[3];
  for (int p = 0; p < 3; ++p) wb[p] = (ushort*)alloc((size_t)C_ * K_CONV * 2);
  ushort* fbuf = (ushort*)alloc((size_t)B_ * N_ * C_ * 2);       // [b][n][c]
  ushort* gbuf = (ushort*)alloc((size_t)B_ * N_ * C_ * 2);       // [b][n][c]
  ushort* hbuf = (ushort*)alloc((size_t)B_ * C_ * N_ * 2);       // [b][c][n]
  float*  sbuf = (float*)alloc((size_t)B_ * C_ * N_ * 4);        // [b][c][n]
  float*  wcat = (float*)alloc(B_ * 256 * 4);
  float*  sebuf = (float*)alloc(B_ * 128 * 4);
  float*  pinv  = (float*)alloc(3 * 128 * 4);
  float*  pbeta = (float*)alloc(3 * 128 * 4);

  for (int p = 0; p < 3; ++p)
    k_prep<<<1, 128, 0, stream>>>(bnw[p], bnb[p], bnm[p], bnv[p], pinv + p * 128, pbeta + p * 128);
  for (int p = 0; p < 3; ++p)
    k_prep_w<<<(C_ * K_CONV + 255) / 256, 256, 0, stream>>>(cw_[p], wb[p]);
  k_prep_y<<<dim3(HP_, B_), 256, 0, stream>>>(x, pinv, pbeta, yp[0], yp[1], yp[2]);

  k_meanx<<<B_ * C_, 256, 0, stream>>>(x, wcat);

  k_conv<<<dim3(N_ / 64, 1, B_), 256, 0, stream>>>(yp[0], wb[0], cbb[0], fbuf, 0);
  k_conv<<<dim3(N_ / 64, 1, B_), 256, 0, stream>>>(yp[1], wb[1], cbb[1], gbuf, 0);
  k_conv<<<dim3(N_ / 64, 1, B_), 256, 0, stream>>>(yp[2], wb[2], cbb[2], hbuf, 1);

  k_scores<<<dim3(N_ / 128, N_ / 128, B_), 256, 0, stream>>>(fbuf, gbuf, attn);
  k_softmax<<<B_ * N_, 256, 0, stream>>>(attn);
  k_sgemm<<<dim3(N_ / 128, 1, B_), 256, 0, stream>>>(hbuf, attn, gamma, sbuf);

  k_means<<<B_ * C_, 256, 0, stream>>>(sbuf, wcat);
  k_se<<<B_, 128, 0, stream>>>(wcat, secw, secb, seuw, seub, sebuf);

  k_final<<<(TOT_OUT + 255) / 256, 256, 0, stream>>>(x, sbuf, sebuf, out);
}